// Round 3
// baseline (455.823 us; speedup 1.0000x reference)
//
#include <hip/hip_runtime.h>
#include <hip/hip_bf16.h>
#include <stdint.h>

typedef unsigned short u16;
typedef __attribute__((ext_vector_type(8))) short short8;   // 8 bf16 = 4 VGPRs
typedef __attribute__((ext_vector_type(4))) float floatx4;

__device__ __forceinline__ u16 f2bf(float f) {
    union { unsigned int i; float f; } v; v.f = f;
    unsigned int r = v.i + 0x7fff + ((v.i >> 16) & 1);  // RNE
    return (u16)(r >> 16);
}

// B=8, CIN=512, COUT=256, H=W=64, K=3, SDIM=512.  All I/O fp32.
// ws layout (bytes):
#define OFF_S    0           // s[b][ci]        8*512 f32
#define OFF_W2   32768       // sum_kk w^2      256*512 f32
#define OFF_BM   1048576     // BmatT[n][k]     1024*4608 bf16 (k-contig per n)
#define OFF_XMT  16777216    // xm NHWC padded  [8][66][66][512] bf16

// ============================================================================
// k_pre: single fused prologue launch, role-split by blockIdx.
//  role fill (bid < 2048): per (b, h-pair, ci-group-64): recompute style s for
//    its 64 ci (wave-coalesced dot + shuffle tree, bitwise == old k_style),
//    write modulated bf16 NHWC tile + zero borders; hp==0 blocks persist S.
//  role bmat (bid >= 2048): composite convT+blur weight matrix (old k_bmat);
//    p==0 blocks also emit W2 rows from the already-staged weight slab.
// ============================================================================
__global__ void k_pre(const float* __restrict__ X, const float* __restrict__ style,
                      const float* __restrict__ mw, const float* __restrict__ mb,
                      const float* __restrict__ Wt, float* __restrict__ W2,
                      float* __restrict__ S, u16* __restrict__ Bm,
                      u16* __restrict__ XMT) {
    __shared__ __align__(16) char sm[20736];
    const int bid = blockIdx.x;
    const int t = threadIdx.x;

    if (bid < 2048) {
        // ---------------- fill role ----------------
        u16 (*tile)[64][80] = (u16 (*)[64][80])sm;       // [2][64][80] u16 = 20480B
        float* sbuf = (float*)(sm + 20480);              // 64 f32
        const int g = bid & 7, hp = (bid >> 3) & 31, b = bid >> 8;
        const int h0 = hp * 2;
        const int lane = t & 63, wv = t >> 6;
        {   // style: s[b, g*64 + cl] for cl in 0..63 (16 per wave)
            const float* st = style + b * 512 + lane * 8;
            float4 s0 = *(const float4*)st;
            float4 s1 = *(const float4*)(st + 4);
            for (int j = 0; j < 16; ++j) {
                int cl = wv * 16 + j;
                const float* wr = mw + (g * 64 + cl) * 512 + lane * 8;
                float4 w0 = *(const float4*)wr;
                float4 w1 = *(const float4*)(wr + 4);
                float a = s0.x * w0.x + s0.y * w0.y + s0.z * w0.z + s0.w * w0.w
                        + s1.x * w1.x + s1.y * w1.y + s1.z * w1.z + s1.w * w1.w;
                #pragma unroll
                for (int o = 32; o; o >>= 1) a += __shfl_xor(a, o, 64);
                if (lane == 0) sbuf[cl] = a * 0.044194173824159216f + mb[g * 64 + cl];
            }
        }
        __syncthreads();
        if (hp == 0 && t < 64) S[b * 512 + g * 64 + t] = sbuf[t];
        // zero borders
        #pragma unroll
        for (int hh = 0; hh < 2; ++hh) {
            int h = h0 + hh;
            if (t < 16) {
                int x = (t >> 3) ? 65 : 0;
                int c8 = t & 7;
                *(short8*)(XMT + ((size_t)(b * 66 + h + 1) * 66 + x) * 512 + g * 64 + c8 * 8) = (short8)0;
            }
            if (h == 0 || h == 63) {
                int y = (h == 0) ? 0 : 65;
                for (int s0i = t; s0i < 528; s0i += 256) {     // 66 x * 8 chunks
                    int x = s0i >> 3, c8 = s0i & 7;
                    *(short8*)(XMT + ((size_t)(b * 66 + y) * 66 + x) * 512 + g * 64 + c8 * 8) = (short8)0;
                }
            }
        }
        // load + modulate + bf16, chunk-XOR swizzled LDS (2-way writes, b128 reads)
        #pragma unroll
        for (int it = 0; it < 8; ++it) {
            int idx = it * 256 + t;                      // 2 hh * 64 ci * 16 chunks
            int hh = idx >> 10, idx2 = idx & 1023;
            int ci_l = idx2 >> 4, ch = idx2 & 15;
            float4 v = *(const float4*)(X + (((b * 512 + g * 64 + ci_l) * 64 + h0 + hh) * 64 + ch * 4));
            float s = sbuf[ci_l];
            int cisw = ci_l ^ ((ch & 7) << 3);
            tile[hh][ch * 4 + 0][cisw] = f2bf(v.x * s);
            tile[hh][ch * 4 + 1][cisw] = f2bf(v.y * s);
            tile[hh][ch * 4 + 2][cisw] = f2bf(v.z * s);
            tile[hh][ch * 4 + 3][cisw] = f2bf(v.w * s);
        }
        __syncthreads();
        #pragma unroll
        for (int it = 0; it < 4; ++it) {
            int idx = it * 256 + t;                      // 2 hh * 64 w * 8 chunks
            int hh = idx >> 9, idx2 = idx & 511;
            int wl_ = idx2 >> 3, c8 = idx2 & 7;
            short8 v = *(const short8*)(&tile[hh][wl_][(c8 ^ ((wl_ >> 2) & 7)) * 8]);
            *(short8*)(XMT + (((size_t)(b * 66 + h0 + hh + 1) * 66 + (wl_ + 1)) * 512 + g * 64 + c8 * 8)) = v;
        }
    } else {
        // ---------------- bmat (+W2) role ----------------
        float* wl2 = (float*)sm;                         // 2304 f32 = 9216B
        const int bq = bid - 2048;                       // 2048 = 4 p * 256 co * 2 ci-halves
        const int ci0 = (bq & 1) * 256;
        const int co  = (bq >> 1) & 255;
        const int p   = bq >> 9;                         // 0..3
        const int py = p >> 1, px = p & 1;
        int wbase = co * 4608 + ci0 * 9;
        #pragma unroll
        for (int j = 0; j < 9; ++j) wl2[j * 256 + t] = Wt[wbase + j * 256 + t];
        __syncthreads();
        if (p == 0) {                                    // W2[co, ci0+t] byproduct
            float a = 0.f;
            #pragma unroll
            for (int j = 0; j < 9; ++j) { float v = wl2[t * 9 + j]; a += v * v; }
            W2[co * 512 + ci0 + t] = a;
        }
        const float KT[2][3][3] = {
            {{0.f,1.f,3.f},{3.f,3.f,1.f},{1.f,0.f,0.f}},   // even output rows
            {{0.f,0.f,1.f},{1.f,3.f,3.f},{3.f,1.f,0.f}}    // odd output rows
        };
        float wv[3][3];
        #pragma unroll
        for (int a = 0; a < 3; ++a)
            #pragma unroll
            for (int bq2 = 0; bq2 < 3; ++bq2) wv[a][bq2] = wl2[t * 9 + a * 3 + bq2];
        int ci = ci0 + t;
        int n = py * 512 + co * 2 + px;
        size_t base = (size_t)n * 4608 + ci;
        #pragma unroll
        for (int dyi = 0; dyi < 3; ++dyi) {
            #pragma unroll
            for (int dxi = 0; dxi < 3; ++dxi) {
                float val = 0.f;
                #pragma unroll
                for (int a = 0; a < 3; ++a) {
                    float ky = KT[py][dyi][a];
                    #pragma unroll
                    for (int bq2 = 0; bq2 < 3; ++bq2)
                        val += wv[a][bq2] * (ky * KT[px][dxi][bq2]);
                }
                Bm[base + (dyi * 3 + dxi) * 512] = f2bf(val * 0.0625f);
            }
        }
    }
}

// ============================================================================
// main implicit GEMM, 256x256-tile 8-phase pipeline (T2+T3+T4+T5):
// M=32768 (b,r,c) x N=1024 (py,co,px) x K=4608 (dy,dx,ci), BK=64, 72 K-tiles.
// 8 waves (2M x 4N), per-wave 128x64 out as 2 M-halves x 2 N-halves of 16x16 frags.
// LDS 128 KiB: A[2 dbuf][256][64] + B[2 dbuf][256][64] bf16, staged in 16 KB
// half-tiles (128 rows) via global_load_lds w/ pre-swizzled source (chunk^=row&7).
// Counted vmcnt(4) at phases 4/8 only; raw s_barrier (no drain); setprio on MFMA.
// Demod (old k_demod) fused into the store epilogue: D from W2 x S^2, L2-hot.
// ============================================================================

#define GLDS(SRC, DST) __builtin_amdgcn_global_load_lds( \
    (const __attribute__((address_space(1))) void*)(SRC), \
    (__attribute__((address_space(3))) void*)(DST), 16, 0, 0)

#define BAR() do { asm volatile("" ::: "memory"); \
                   __builtin_amdgcn_s_barrier(); \
                   asm volatile("" ::: "memory"); } while (0)

#define WAITV(n) asm volatile("s_waitcnt vmcnt(" #n ")" ::: "memory")

// stage one 128-row half-tile (2 x global_load_lds per thread)
#define STAGE_A(d, h, kt) do { int _o = offA(kt); \
    GLDS(X  + preA[h][0] + _o, smem + (d)*32768 + (h)*16384 + t*16); \
    GLDS(X  + preA[h][1] + _o, smem + (d)*32768 + (h)*16384 + 8192 + t*16); \
  } while (0)
#define STAGE_B(d, h, kt) do { int _o = (kt)*64; \
    GLDS(Bm + preB[h][0] + _o, smem + 65536 + (d)*32768 + (h)*16384 + t*16); \
    GLDS(Bm + preB[h][1] + _o, smem + 65536 + (d)*32768 + (h)*16384 + 8192 + t*16); \
  } while (0)

// register-subtile loads (swizzled ds_read_b128)
#define LOAD_A(d, mh) do { \
    _Pragma("unroll") \
    for (int mt_ = 0; mt_ < 4; ++mt_) { \
      afr[mt_][0] = *(const short8*)(smem + (d)*32768 + (mh)*16384 + mt_*2048 + baseMA + cb0); \
      afr[mt_][1] = *(const short8*)(smem + (d)*32768 + (mh)*16384 + mt_*2048 + baseMA + cb1); \
    } } while (0)
#define LOAD_B(d, nh, DST) do { \
    _Pragma("unroll") \
    for (int nt_ = 0; nt_ < 2; ++nt_) { \
      DST[nt_][0] = *(const short8*)(smem + 65536 + (d)*32768 + (nh)*16384 + nt_*2048 + baseNB + cb0); \
      DST[nt_][1] = *(const short8*)(smem + 65536 + (d)*32768 + (nh)*16384 + nt_*2048 + baseNB + cb1); \
    } } while (0)

// one C-quadrant x K=64 : 16 MFMA, setprio-wrapped (T5)
#define MMA(mh, nh, BF) do { \
    __builtin_amdgcn_s_setprio(1); \
    _Pragma("unroll") \
    for (int mt_ = 0; mt_ < 4; ++mt_) \
      _Pragma("unroll") \
      for (int nt_ = 0; nt_ < 2; ++nt_) { \
        acc[mh][mt_][nh][nt_] = __builtin_amdgcn_mfma_f32_16x16x32_bf16( \
            afr[mt_][0], BF[nt_][0], acc[mh][mt_][nh][nt_], 0, 0, 0); \
        acc[mh][mt_][nh][nt_] = __builtin_amdgcn_mfma_f32_16x16x32_bf16( \
            afr[mt_][1], BF[nt_][1], acc[mh][mt_][nh][nt_], 0, 0, 0); \
      } \
    __builtin_amdgcn_s_setprio(0); \
  } while (0)

__global__ __launch_bounds__(512, 2)
void k_main8(const u16* __restrict__ X, const u16* __restrict__ Bm,
             const float* __restrict__ W2, const float* __restrict__ S,
             float* __restrict__ out) {
    __shared__ __align__(16) char smem[131072];
    const int t = threadIdx.x;
    // XCD-aware swizzle (512 = 8*64, bijective); bn fastest for A-tile L2 reuse.
    const int swz = (blockIdx.x & 7) * 64 + (blockIdx.x >> 3);
    const int bn = swz & 3, bm = swz >> 2;
    const int w = t >> 6, L = t & 63;
    const int wm = w >> 2, wn = w & 3;
    const int quad = L >> 4, col = L & 15;

    // staging precompute: slot sigma=i*512+t -> row ml=sigma>>3, phys chunk pc=sigma&7
    // holds logical k-chunk ks = pc ^ (ml&7)  (XOR swizzle via pre-swizzled source)
    int preA[2][2], preB[2][2];
    #pragma unroll
    for (int h = 0; h < 2; ++h)
      #pragma unroll
      for (int i = 0; i < 2; ++i) {
        int sig = i * 512 + t;
        int ml = sig >> 3;
        int ks = (sig & 7) ^ (ml & 7);
        int mg = bm * 256 + h * 128 + ml;
        int b_ = mg >> 12, r = (mg >> 6) & 63, c = mg & 63;
        preA[h][i] = ((b_ * 66 + r) * 66 + c) * 512 + ks * 8;
        int ng = bn * 256 + h * 128 + ml;
        preB[h][i] = ng * 4608 + ks * 8;
      }
    auto offA = [](int kt) {
        int j = kt >> 3;
        int dy = (j * 11) >> 5;          // j/3 for j in 0..8
        int dx = j - dy * 3;
        return (dy * 66 + dx) * 512 + (kt & 7) * 64;
    };

    // fragment read bases; swizzle XOR value is col&7 (all other row terms = 0 mod 8)
    const int baseMA = (wm * 64 + col) * 128;
    const int baseNB = (wn * 32 + col) * 128;
    const int cb0 = ((0 * 4 + quad) ^ (col & 7)) * 16;
    const int cb1 = ((1 * 4 + quad) ^ (col & 7)) * 16;

    short8 afr[4][2], bf0[2][2], bf1[2][2];
    floatx4 acc[2][4][2][2];
    #pragma unroll
    for (int mh = 0; mh < 2; ++mh)
      #pragma unroll
      for (int mt = 0; mt < 4; ++mt)
        #pragma unroll
        for (int nh = 0; nh < 2; ++nh)
          #pragma unroll
          for (int nt = 0; nt < 2; ++nt)
            acc[mh][mt][nh][nt] = (floatx4){0.f, 0.f, 0.f, 0.f};

    // ---- prologue: tile0 fully (buf0) + tile1 h0 halves (buf1)
    STAGE_A(0, 0, 0); STAGE_B(0, 0, 0);
    STAGE_A(0, 1, 0); STAGE_B(0, 1, 0);
    STAGE_A(1, 0, 1); STAGE_B(1, 0, 1);
    WAITV(4);                 // tile0 landed; A0[1],B0[1] may remain in flight
    BAR();

    // ---- main loop: 35 iters x 2 K-tiles (tiles 0..69), stages reach tile 71
    #pragma unroll 1
    for (int it = 0; it < 35; ++it) {
        const int k = 2 * it;
        // P1: tile k Q(0,0)
        LOAD_A(0, 0); LOAD_B(0, 0, bf0);
        STAGE_A(1, 1, k + 1);
        BAR(); MMA(0, 0, bf0); BAR();
        // P2: Q(0,1)
        LOAD_B(0, 1, bf1);
        STAGE_B(1, 1, k + 1);
        BAR(); MMA(0, 1, bf1); BAR();
        // P3: Q(1,0)
        LOAD_A(0, 1);
        STAGE_A(0, 0, k + 2);
        BAR(); MMA(1, 0, bf0); BAR();
        // P4: Q(1,1)  [wait covers tile k+1 reads in P5..P8]
        STAGE_B(0, 0, k + 2);
        WAITV(4);
        BAR(); MMA(1, 1, bf1); BAR();
        // P5: tile k+1 Q(0,0)
        LOAD_A(1, 0); LOAD_B(1, 0, bf0);
        STAGE_A(0, 1, k + 2);
        BAR(); MMA(0, 0, bf0); BAR();
        // P6: Q(0,1)
        LOAD_B(1, 1, bf1);
        STAGE_B(0, 1, k + 2);
        BAR(); MMA(0, 1, bf1); BAR();
        // P7: Q(1,0)
        LOAD_A(1, 1);
        STAGE_A(1, 0, k + 3);
        BAR(); MMA(1, 0, bf0); BAR();
        // P8: Q(1,1)  [wait covers tile k+2 reads in next P1..P4]
        STAGE_B(1, 0, k + 3);
        WAITV(4);
        BAR(); MMA(1, 1, bf1); BAR();
    }

    // ---- pipeline epilogue: tiles 70 (buf0) and 71 (buf1)
    LOAD_A(0, 0); LOAD_B(0, 0, bf0);
    STAGE_A(1, 1, 71);
    BAR(); MMA(0, 0, bf0); BAR();
    LOAD_B(0, 1, bf1);
    STAGE_B(1, 1, 71);
    BAR(); MMA(0, 1, bf1); BAR();
    LOAD_A(0, 1);
    BAR(); MMA(1, 0, bf0); BAR();
    WAITV(0);                 // drain A0/B0[71] (loop P7/P8) + A1/B1[71] (above)
    BAR(); MMA(1, 1, bf1); BAR();
    LOAD_A(1, 0); LOAD_B(1, 0, bf0);
    BAR(); MMA(0, 0, bf0); BAR();
    LOAD_B(1, 1, bf1);
    BAR(); MMA(0, 1, bf1); BAR();
    LOAD_A(1, 1);
    BAR(); MMA(1, 0, bf0); BAR();
    BAR(); MMA(1, 1, bf1); BAR();

    // ---- fused demod: D for this block's 128 couts into 512B LDS slot.
    // block output: b = bm>>4, image rows r0..r0+3, py fixed, 128 couts, full x.
    const int b   = bm >> 4;
    const int r0  = (bm & 15) * 4;
    const int py  = bn >> 1;
    const int co0 = (bn & 1) * 128;
    float* dls = (float*)(smem + 130560);           // above ep region [0,67584)
    {
        const float* srow = S + b * 512 + L * 8;
        float4 sa = *(const float4*)srow;
        float4 sb = *(const float4*)(srow + 4);
        float s2_0 = sa.x * sa.x, s2_1 = sa.y * sa.y, s2_2 = sa.z * sa.z, s2_3 = sa.w * sa.w;
        float s2_4 = sb.x * sb.x, s2_5 = sb.y * sb.y, s2_6 = sb.z * sb.z, s2_7 = sb.w * sb.w;
        for (int j = 0; j < 16; ++j) {
            int co_r = w * 16 + j;                  // 8 waves x 16 = 128 couts
            const float* wr = W2 + (co0 + co_r) * 512 + L * 8;
            float4 wa = *(const float4*)wr;
            float4 wb = *(const float4*)(wr + 4);
            float a = wa.x * s2_0 + wa.y * s2_1 + wa.z * s2_2 + wa.w * s2_3
                    + wb.x * s2_4 + wb.y * s2_5 + wb.z * s2_6 + wb.w * s2_7;
            #pragma unroll
            for (int o = 32; o; o >>= 1) a += __shfl_xor(a, o, 64);
            if (L == 0) dls[co_r] = 0.014731391274719738f * rsqrtf(a * (1.0f / 4608.0f) + 1e-8f);
        }
    }
    __syncthreads();
    float dvals[2][2];
    #pragma unroll
    for (int nh = 0; nh < 2; ++nh)
      #pragma unroll
      for (int nt = 0; nt < 2; ++nt)
        dvals[nh][nt] = dls[nh * 64 + wn * 16 + nt * 8 + (col >> 1)];

    // ---- store epilogue: scale by D, LDS-transpose per image row, float4 stores.
    float* ep = (float*)smem;                       // [128 co][132] f32 (16B-aligned rows)
    #pragma unroll
    for (int rl = 0; rl < 4; ++rl) {                // image row r0+rl; y = 2*(r0+rl)+py
        if (wm == (rl & 1)) {
            const int mh = rl >> 1;                 // lane's M-row = mh*128+wm*64+... -> rl = mh*2+wm
            #pragma unroll
            for (int nh = 0; nh < 2; ++nh)
              #pragma unroll
              for (int nt = 0; nt < 2; ++nt) {
                float dsv = dvals[nh][nt];
                int coL = nh * 64 + wn * 16 + nt * 8 + (col >> 1);
                #pragma unroll
                for (int mt = 0; mt < 4; ++mt)
                  #pragma unroll
                  for (int reg = 0; reg < 4; ++reg) {
                    int x = 2 * (mt * 16 + quad * 4 + reg) + (col & 1);
                    ep[coL * 132 + x] = acc[mh][mt][nh][nt][reg] * dsv;
                  }
              }
        }
        __syncthreads();
        #pragma unroll
        for (int itc = 0; itc < 8; ++itc) {
            int s = itc * 512 + t;                  // 4096 float4 slots = 128 co x 32
            int co = s >> 5, xi = s & 31;
            float4 v = *(const float4*)(ep + co * 132 + xi * 4);
            size_t o = ((size_t)((b * 256 + co0 + co) * 128 + (2 * (r0 + rl) + py))) * 128 + xi * 4;
            *(float4*)(out + o) = v;
        }
        __syncthreads();
    }
}

extern "C" void kernel_launch(void* const* d_in, const int* in_sizes, int n_in,
                              void* d_out, int out_size, void* d_ws, size_t ws_size,
                              hipStream_t stream) {
    const float* x      = (const float*)d_in[0];   // [8,512,64,64] f32
    const float* style  = (const float*)d_in[1];   // [8,512]
    const float* weight = (const float*)d_in[2];   // [1,256,512,3,3]
    const float* mw     = (const float*)d_in[3];   // [512,512]
    const float* mb     = (const float*)d_in[4];   // [512]
    float* out = (float*)d_out;                    // [8,256,128,128] f32
    char* ws = (char*)d_ws;
    float* S   = (float*)(ws + OFF_S);
    float* W2  = (float*)(ws + OFF_W2);
    u16*  BM   = (u16*)(ws + OFF_BM);
    u16*  XMT  = (u16*)(ws + OFF_XMT);

    k_pre  <<<4096, 256, 0, stream>>>(x, style, mw, mb, weight, W2, S, BM, XMT);
    k_main8<<<512,  512, 0, stream>>>(XMT, BM, W2, S, out);
}

// Round 4
// 424.557 us; speedup vs baseline: 1.0736x; 1.0736x over previous
//
#include <hip/hip_runtime.h>
#include <hip/hip_bf16.h>
#include <stdint.h>

typedef unsigned short u16;
typedef __attribute__((ext_vector_type(8))) short short8;   // 8 bf16 = 4 VGPRs
typedef __attribute__((ext_vector_type(4))) float floatx4;

__device__ __forceinline__ u16 f2bf(float f) {
    union { unsigned int i; float f; } v; v.f = f;
    unsigned int r = v.i + 0x7fff + ((v.i >> 16) & 1);  // RNE
    return (u16)(r >> 16);
}

// B=8, CIN=512, COUT=256, H=W=64, K=3, SDIM=512.  All I/O fp32.
// ws layout (bytes):
#define OFF_S    0           // s[b][ci]        8*512 f32
#define OFF_DEM  16384       // scale*demod     8*256 f32
#define OFF_W2   32768       // sum_kk w^2      256*512 f32
#define OFF_BM   1048576     // BmatT[n][k]     1024*4608 bf16 (k-contig per n)
#define OFF_XMT  16777216    // xm NHWC padded  [8][66][66][512] bf16

// ============================================================================
// k_pre1: layer-1 prologue, role-split (all roles independent, no recompute):
//   bid <  1024 : style  (R2 k_style body)  -> S
//   bid <  1536 : w2     (R2 k_w2 body)     -> W2
//   else        : bmat   (R2 k_bmat body)   -> BM
// ============================================================================
__global__ void k_pre1(const float* __restrict__ style, const float* __restrict__ mw,
                       const float* __restrict__ mb, const float* __restrict__ Wt,
                       float* __restrict__ S, float* __restrict__ W2,
                       u16* __restrict__ Bm) {
    __shared__ float wl2[2304];                      // bmat role only (9216B)
    const int bid = blockIdx.x;
    const int tid = threadIdx.x;

    if (bid < 1024) {
        // ---- style: one wave per (b,ci), lanes span d, shuffle reduce
        int g = bid * 4 + (tid >> 6);                // 4096 waves
        int lane = tid & 63;
        int b = g >> 9, ci = g & 511;
        const float* sr = style + b * 512 + lane * 8;
        const float* wr = mw + ci * 512 + lane * 8;
        float4 s0 = *(const float4*)(sr);
        float4 s1 = *(const float4*)(sr + 4);
        float4 w0 = *(const float4*)(wr);
        float4 w1 = *(const float4*)(wr + 4);
        float acc = s0.x * w0.x + s0.y * w0.y + s0.z * w0.z + s0.w * w0.w
                  + s1.x * w1.x + s1.y * w1.y + s1.z * w1.z + s1.w * w1.w;
        #pragma unroll
        for (int o = 32; o; o >>= 1) acc += __shfl_xor(acc, o, 64);
        if (lane == 0) S[g] = acc * 0.044194173824159216f + mb[ci];
    } else if (bid < 1536) {
        // ---- w2[co,ci] = sum over 3x3 of weight^2
        int t = (bid - 1024) * 256 + tid;            // 131072
        const float* p = Wt + t * 9;
        float a = 0.f;
        #pragma unroll
        for (int i = 0; i < 9; ++i) { float v = p[i]; a += v * v; }
        W2[t] = a;
    } else {
        // ---- bmat: weights staged through LDS with coalesced loads
        const int bq = bid - 1536;                   // 2048 = 4 p * 256 co * 2 ci-halves
        const int ci0 = (bq & 1) * 256;
        const int co  = (bq >> 1) & 255;
        const int p   = bq >> 9;                     // 0..3
        const int py = p >> 1, px = p & 1;
        int wbase = co * 4608 + ci0 * 9;
        #pragma unroll
        for (int j = 0; j < 9; ++j) wl2[j * 256 + tid] = Wt[wbase + j * 256 + tid];
        __syncthreads();
        const float KT[2][3][3] = {
            {{0.f,1.f,3.f},{3.f,3.f,1.f},{1.f,0.f,0.f}},   // even output rows
            {{0.f,0.f,1.f},{1.f,3.f,3.f},{3.f,1.f,0.f}}    // odd output rows
        };
        float wv[3][3];
        #pragma unroll
        for (int a = 0; a < 3; ++a)
            #pragma unroll
            for (int bq2 = 0; bq2 < 3; ++bq2) wv[a][bq2] = wl2[tid * 9 + a * 3 + bq2];
        int ci = ci0 + tid;
        int n = py * 512 + co * 2 + px;
        size_t base = (size_t)n * 4608 + ci;
        #pragma unroll
        for (int dyi = 0; dyi < 3; ++dyi) {
            #pragma unroll
            for (int dxi = 0; dxi < 3; ++dxi) {
                float val = 0.f;
                #pragma unroll
                for (int a = 0; a < 3; ++a) {
                    float ky = KT[py][dyi][a];
                    #pragma unroll
                    for (int bq2 = 0; bq2 < 3; ++bq2)
                        val += wv[a][bq2] * (ky * KT[px][dxi][bq2]);
                }
                Bm[base + (dyi * 3 + dxi) * 512] = f2bf(val * 0.0625f);
            }
        }
    }
}

// ============================================================================
// k_pre2: layer-2 prologue, role-split (needs S, W2 from k_pre1):
//   bid < 4096 : fill  (R2 k_fill body, incl. borders) -> XMT
//   else       : demod (R2 k_demod body)               -> DEM
// ============================================================================
__global__ void k_pre2(const float* __restrict__ X, const float* __restrict__ S,
                       const float* __restrict__ W2, float* __restrict__ DEM,
                       u16* __restrict__ XMT) {
    __shared__ __align__(16) u16 tile[64][80];           // fill role only (10240B)
    const int bid = blockIdx.x;
    const int t = threadIdx.x;

    if (bid < 4096) {
        // ---- fill: xmt[b][y][x][ci] = x[b][ci][y-1][x-1] * s[b][ci], + borders
        int ci0g = (bid & 7) * 64;
        int h = (bid >> 3) & 63;
        int b = bid >> 9;
        if (t < 16) {
            int x = (t >> 3) ? 65 : 0;
            int c8 = t & 7;
            *(short8*)(XMT + ((size_t)(b * 66 + h + 1) * 66 + x) * 512 + ci0g + c8 * 8) = (short8)0;
        }
        if (h == 0 || h == 63) {
            int y = (h == 0) ? 0 : 65;
            for (int s0i = t; s0i < 528; s0i += 256) {       // 66 x * 8 chunks
                int x = s0i >> 3, c8 = s0i & 7;
                *(short8*)(XMT + ((size_t)(b * 66 + y) * 66 + x) * 512 + ci0g + c8 * 8) = (short8)0;
            }
        }
        #pragma unroll
        for (int it = 0; it < 4; ++it) {
            int idx = it * 256 + t;                          // 64 ci * 16 chunks of 4 w
            int ci_l = idx >> 4, ch = idx & 15;
            float4 v = *(const float4*)(X + (((b * 512 + ci0g + ci_l) * 64 + h) * 64 + ch * 4));
            float s = S[b * 512 + ci0g + ci_l];
            int cisw = ci_l ^ ((ch & 7) << 3);               // chunk-XOR swizzle
            tile[ch * 4 + 0][cisw] = f2bf(v.x * s);
            tile[ch * 4 + 1][cisw] = f2bf(v.y * s);
            tile[ch * 4 + 2][cisw] = f2bf(v.z * s);
            tile[ch * 4 + 3][cisw] = f2bf(v.w * s);
        }
        __syncthreads();
        #pragma unroll
        for (int it = 0; it < 2; ++it) {
            int idx = it * 256 + t;                          // 64 w * 8 chunks of 8
            int wl = idx >> 3, c8 = idx & 7;
            short8 v = *(const short8*)(&tile[wl][(c8 ^ ((wl >> 2) & 7)) * 8]);
            *(short8*)(XMT + (((size_t)(b * 66 + h + 1) * 66 + (wl + 1)) * 512 + ci0g + c8 * 8)) = v;
        }
    } else {
        // ---- demod: one wave per (b,co), lanes span ci, shuffle reduce
        int g = (bid - 4096) * 4 + (t >> 6);                 // 2048 waves
        int lane = t & 63;
        int b = g >> 8, co = g & 255;
        const float* wr = W2 + co * 512 + lane * 8;
        const float* sr = S + b * 512 + lane * 8;
        float4 w0 = *(const float4*)(wr);
        float4 w1 = *(const float4*)(wr + 4);
        float4 s0 = *(const float4*)(sr);
        float4 s1 = *(const float4*)(sr + 4);
        float a = w0.x * s0.x * s0.x + w0.y * s0.y * s0.y + w0.z * s0.z * s0.z + w0.w * s0.w * s0.w
                + w1.x * s1.x * s1.x + w1.y * s1.y * s1.y + w1.z * s1.z * s1.z + w1.w * s1.w * s1.w;
        #pragma unroll
        for (int o = 32; o; o >>= 1) a += __shfl_xor(a, o, 64);
        if (lane == 0) DEM[g] = 0.014731391274719738f * rsqrtf(a * (1.0f / 4608.0f) + 1e-8f);
    }
}

// ============================================================================
// main implicit GEMM, 256x256-tile 8-phase pipeline (T2+T3+T4+T5):
// M=32768 (b,r,c) x N=1024 (py,co,px) x K=4608 (dy,dx,ci), BK=64, 72 K-tiles.
// 8 waves (2M x 4N), per-wave 128x64 out as 2 M-halves x 2 N-halves of 16x16 frags.
// LDS 128 KiB: A[2 dbuf][256][64] + B[2 dbuf][256][64] bf16, staged in 16 KB
// half-tiles (128 rows) via global_load_lds w/ pre-swizzled source (chunk^=row&7).
// Counted vmcnt(4) at phases 4/8 only; raw s_barrier (no drain); setprio on MFMA.
// ============================================================================

#define GLDS(SRC, DST) __builtin_amdgcn_global_load_lds( \
    (const __attribute__((address_space(1))) void*)(SRC), \
    (__attribute__((address_space(3))) void*)(DST), 16, 0, 0)

#define BAR() do { asm volatile("" ::: "memory"); \
                   __builtin_amdgcn_s_barrier(); \
                   asm volatile("" ::: "memory"); } while (0)

#define WAITV(n) asm volatile("s_waitcnt vmcnt(" #n ")" ::: "memory")

// stage one 128-row half-tile (2 x global_load_lds per thread)
#define STAGE_A(d, h, kt) do { int _o = offA(kt); \
    GLDS(X  + preA[h][0] + _o, smem + (d)*32768 + (h)*16384 + t*16); \
    GLDS(X  + preA[h][1] + _o, smem + (d)*32768 + (h)*16384 + 8192 + t*16); \
  } while (0)
#define STAGE_B(d, h, kt) do { int _o = (kt)*64; \
    GLDS(Bm + preB[h][0] + _o, smem + 65536 + (d)*32768 + (h)*16384 + t*16); \
    GLDS(Bm + preB[h][1] + _o, smem + 65536 + (d)*32768 + (h)*16384 + 8192 + t*16); \
  } while (0)

// register-subtile loads (swizzled ds_read_b128)
#define LOAD_A(d, mh) do { \
    _Pragma("unroll") \
    for (int mt_ = 0; mt_ < 4; ++mt_) { \
      afr[mt_][0] = *(const short8*)(smem + (d)*32768 + (mh)*16384 + mt_*2048 + baseMA + cb0); \
      afr[mt_][1] = *(const short8*)(smem + (d)*32768 + (mh)*16384 + mt_*2048 + baseMA + cb1); \
    } } while (0)
#define LOAD_B(d, nh, DST) do { \
    _Pragma("unroll") \
    for (int nt_ = 0; nt_ < 2; ++nt_) { \
      DST[nt_][0] = *(const short8*)(smem + 65536 + (d)*32768 + (nh)*16384 + nt_*2048 + baseNB + cb0); \
      DST[nt_][1] = *(const short8*)(smem + 65536 + (d)*32768 + (nh)*16384 + nt_*2048 + baseNB + cb1); \
    } } while (0)

// one C-quadrant x K=64 : 16 MFMA, setprio-wrapped (T5)
#define MMA(mh, nh, BF) do { \
    __builtin_amdgcn_s_setprio(1); \
    _Pragma("unroll") \
    for (int mt_ = 0; mt_ < 4; ++mt_) \
      _Pragma("unroll") \
      for (int nt_ = 0; nt_ < 2; ++nt_) { \
        acc[mh][mt_][nh][nt_] = __builtin_amdgcn_mfma_f32_16x16x32_bf16( \
            afr[mt_][0], BF[nt_][0], acc[mh][mt_][nh][nt_], 0, 0, 0); \
        acc[mh][mt_][nh][nt_] = __builtin_amdgcn_mfma_f32_16x16x32_bf16( \
            afr[mt_][1], BF[nt_][1], acc[mh][mt_][nh][nt_], 0, 0, 0); \
      } \
    __builtin_amdgcn_s_setprio(0); \
  } while (0)

__global__ __launch_bounds__(512, 2)
void k_main8(const u16* __restrict__ X, const u16* __restrict__ Bm,
             const float* __restrict__ D, float* __restrict__ out) {
    __shared__ __align__(16) char smem[131072];
    const int t = threadIdx.x;
    // XCD-aware swizzle (512 = 8*64, bijective); bn fastest for A-tile L2 reuse.
    const int swz = (blockIdx.x & 7) * 64 + (blockIdx.x >> 3);
    const int bn = swz & 3, bm = swz >> 2;
    const int w = t >> 6, L = t & 63;
    const int wm = w >> 2, wn = w & 3;
    const int quad = L >> 4, col = L & 15;

    // staging precompute: slot sigma=i*512+t -> row ml=sigma>>3, phys chunk pc=sigma&7
    // holds logical k-chunk ks = pc ^ (ml&7)  (XOR swizzle via pre-swizzled source)
    int preA[2][2], preB[2][2];
    #pragma unroll
    for (int h = 0; h < 2; ++h)
      #pragma unroll
      for (int i = 0; i < 2; ++i) {
        int sig = i * 512 + t;
        int ml = sig >> 3;
        int ks = (sig & 7) ^ (ml & 7);
        int mg = bm * 256 + h * 128 + ml;
        int b_ = mg >> 12, r = (mg >> 6) & 63, c = mg & 63;
        preA[h][i] = ((b_ * 66 + r) * 66 + c) * 512 + ks * 8;
        int ng = bn * 256 + h * 128 + ml;
        preB[h][i] = ng * 4608 + ks * 8;
      }
    auto offA = [](int kt) {
        int j = kt >> 3;
        int dy = (j * 11) >> 5;          // j/3 for j in 0..8
        int dx = j - dy * 3;
        return (dy * 66 + dx) * 512 + (kt & 7) * 64;
    };

    // fragment read bases; swizzle XOR value is col&7 (all other row terms = 0 mod 8)
    const int baseMA = (wm * 64 + col) * 128;
    const int baseNB = (wn * 32 + col) * 128;
    const int cb0 = ((0 * 4 + quad) ^ (col & 7)) * 16;
    const int cb1 = ((1 * 4 + quad) ^ (col & 7)) * 16;

    short8 afr[4][2], bf0[2][2], bf1[2][2];
    floatx4 acc[2][4][2][2];
    #pragma unroll
    for (int mh = 0; mh < 2; ++mh)
      #pragma unroll
      for (int mt = 0; mt < 4; ++mt)
        #pragma unroll
        for (int nh = 0; nh < 2; ++nh)
          #pragma unroll
          for (int nt = 0; nt < 2; ++nt)
            acc[mh][mt][nh][nt] = (floatx4){0.f, 0.f, 0.f, 0.f};

    // ---- prologue: tile0 fully (buf0) + tile1 h0 halves (buf1)
    STAGE_A(0, 0, 0); STAGE_B(0, 0, 0);
    STAGE_A(0, 1, 0); STAGE_B(0, 1, 0);
    STAGE_A(1, 0, 1); STAGE_B(1, 0, 1);
    WAITV(4);                 // tile0 landed; A0[1],B0[1] may remain in flight
    BAR();

    // ---- main loop: 35 iters x 2 K-tiles (tiles 0..69), stages reach tile 71
    #pragma unroll 1
    for (int it = 0; it < 35; ++it) {
        const int k = 2 * it;
        // P1: tile k Q(0,0)
        LOAD_A(0, 0); LOAD_B(0, 0, bf0);
        STAGE_A(1, 1, k + 1);
        BAR(); MMA(0, 0, bf0); BAR();
        // P2: Q(0,1)
        LOAD_B(0, 1, bf1);
        STAGE_B(1, 1, k + 1);
        BAR(); MMA(0, 1, bf1); BAR();
        // P3: Q(1,0)
        LOAD_A(0, 1);
        STAGE_A(0, 0, k + 2);
        BAR(); MMA(1, 0, bf0); BAR();
        // P4: Q(1,1)  [wait covers tile k+1 reads in P5..P8]
        STAGE_B(0, 0, k + 2);
        WAITV(4);
        BAR(); MMA(1, 1, bf1); BAR();
        // P5: tile k+1 Q(0,0)
        LOAD_A(1, 0); LOAD_B(1, 0, bf0);
        STAGE_A(0, 1, k + 2);
        BAR(); MMA(0, 0, bf0); BAR();
        // P6: Q(0,1)
        LOAD_B(1, 1, bf1);
        STAGE_B(0, 1, k + 2);
        BAR(); MMA(0, 1, bf1); BAR();
        // P7: Q(1,0)
        LOAD_A(1, 1);
        STAGE_A(1, 0, k + 3);
        BAR(); MMA(1, 0, bf0); BAR();
        // P8: Q(1,1)  [wait covers tile k+2 reads in next P1..P4]
        STAGE_B(1, 0, k + 3);
        WAITV(4);
        BAR(); MMA(1, 1, bf1); BAR();
    }

    // ---- pipeline epilogue: tiles 70 (buf0) and 71 (buf1)
    LOAD_A(0, 0); LOAD_B(0, 0, bf0);
    STAGE_A(1, 1, 71);
    BAR(); MMA(0, 0, bf0); BAR();
    LOAD_B(0, 1, bf1);
    STAGE_B(1, 1, 71);
    BAR(); MMA(0, 1, bf1); BAR();
    LOAD_A(0, 1);
    BAR(); MMA(1, 0, bf0); BAR();
    WAITV(0);                 // drain A0/B0[71] (loop P7/P8) + A1/B1[71] (above)
    BAR(); MMA(1, 1, bf1); BAR();
    LOAD_A(1, 0); LOAD_B(1, 0, bf0);
    BAR(); MMA(0, 0, bf0); BAR();
    LOAD_B(1, 1, bf1);
    BAR(); MMA(0, 1, bf1); BAR();
    LOAD_A(1, 1);
    BAR(); MMA(1, 0, bf0); BAR();
    BAR(); MMA(1, 1, bf1); BAR();

    // ---- store epilogue: scale by D, LDS-transpose per image row, float4 stores.
    // block output: b = bm>>4, image rows r0..r0+3, py fixed, 128 couts, full x.
    const int b   = bm >> 4;
    const int r0  = (bm & 15) * 4;
    const int py  = bn >> 1;
    const int co0 = (bn & 1) * 128;
    float dvals[2][2];
    #pragma unroll
    for (int nh = 0; nh < 2; ++nh)
      #pragma unroll
      for (int nt = 0; nt < 2; ++nt)
        dvals[nh][nt] = D[b * 256 + co0 + nh * 64 + wn * 16 + nt * 8 + (col >> 1)];

    float* ep = (float*)smem;                       // [128 co][132] f32 (16B-aligned rows)
    #pragma unroll
    for (int rl = 0; rl < 4; ++rl) {                // image row r0+rl; y = 2*(r0+rl)+py
        if (wm == (rl & 1)) {
            const int mh = rl >> 1;                 // lane's M-row = mh*128+wm*64+... -> rl = mh*2+wm
            #pragma unroll
            for (int nh = 0; nh < 2; ++nh)
              #pragma unroll
              for (int nt = 0; nt < 2; ++nt) {
                float dsv = dvals[nh][nt];
                int coL = nh * 64 + wn * 16 + nt * 8 + (col >> 1);
                #pragma unroll
                for (int mt = 0; mt < 4; ++mt)
                  #pragma unroll
                  for (int reg = 0; reg < 4; ++reg) {
                    int x = 2 * (mt * 16 + quad * 4 + reg) + (col & 1);
                    ep[coL * 132 + x] = acc[mh][mt][nh][nt][reg] * dsv;
                  }
              }
        }
        __syncthreads();
        #pragma unroll
        for (int itc = 0; itc < 8; ++itc) {
            int s = itc * 512 + t;                  // 4096 float4 slots = 128 co x 32
            int co = s >> 5, xi = s & 31;
            float4 v = *(const float4*)(ep + co * 132 + xi * 4);
            size_t o = ((size_t)((b * 256 + co0 + co) * 128 + (2 * (r0 + rl) + py))) * 128 + xi * 4;
            *(float4*)(out + o) = v;
        }
        __syncthreads();
    }
}

extern "C" void kernel_launch(void* const* d_in, const int* in_sizes, int n_in,
                              void* d_out, int out_size, void* d_ws, size_t ws_size,
                              hipStream_t stream) {
    const float* x      = (const float*)d_in[0];   // [8,512,64,64] f32
    const float* style  = (const float*)d_in[1];   // [8,512]
    const float* weight = (const float*)d_in[2];   // [1,256,512,3,3]
    const float* mw     = (const float*)d_in[3];   // [512,512]
    const float* mb     = (const float*)d_in[4];   // [512]
    float* out = (float*)d_out;                    // [8,256,128,128] f32
    char* ws = (char*)d_ws;
    float* S   = (float*)(ws + OFF_S);
    float* DEM = (float*)(ws + OFF_DEM);
    float* W2  = (float*)(ws + OFF_W2);
    u16*  BM   = (u16*)(ws + OFF_BM);
    u16*  XMT  = (u16*)(ws + OFF_XMT);

    k_pre1 <<<3584, 256, 0, stream>>>(style, mw, mb, weight, S, W2, BM);
    k_pre2 <<<4608, 256, 0, stream>>>(x, S, W2, DEM, XMT);
    k_main8<<<512,  512, 0, stream>>>(XMT, BM, DEM, out);
}